// Round 2
// baseline (545.262 us; speedup 1.0000x reference)
//
#include <hip/hip_runtime.h>

#define N_NODES 100000
#define N_EDGES 1600000
#define NFEAT 256
#define NHID 64
#define NOUT 16

// ---------------------------------------------------------------------------
// K1: support1 = emb @ W1   [100000,256] @ [256,64]
// thread = one row; 64 fp32 accumulators; W1 accesses are threadIdx-free
// (wave-uniform) -> compiler emits s_load; emb row streamed as float4.
// ---------------------------------------------------------------------------
__global__ __launch_bounds__(256) void gemm1_kernel(
    const float* __restrict__ emb, const float* __restrict__ W1,
    float* __restrict__ out) {
  int row = blockIdx.x * blockDim.x + threadIdx.x;
  if (row >= N_NODES) return;
  float acc[NHID];
#pragma unroll
  for (int c = 0; c < NHID; ++c) acc[c] = 0.f;
  const float* er = emb + (size_t)row * NFEAT;
  for (int k = 0; k < NFEAT; k += 4) {
    float4 e = *(const float4*)(er + k);
#pragma unroll
    for (int j = 0; j < 4; ++j) {
      const float* w = W1 + (size_t)(k + j) * NHID;
      float ej = j == 0 ? e.x : (j == 1 ? e.y : (j == 2 ? e.z : e.w));
#pragma unroll
      for (int c = 0; c < NHID; ++c) acc[c] = fmaf(ej, w[c], acc[c]);
    }
  }
  float* o = out + (size_t)row * NHID;
#pragma unroll
  for (int c = 0; c < NHID; c += 4) {
    float4 v = {acc[c], acc[c + 1], acc[c + 2], acc[c + 3]};
    *(float4*)(o + c) = v;
  }
}

// ---------------------------------------------------------------------------
// K2: hacc[dst] += edge_val * support1[src]   (64-wide rows, 1 wave per edge)
// ---------------------------------------------------------------------------
__global__ __launch_bounds__(256) void spmm1_kernel(
    const float* __restrict__ support1, const float* __restrict__ edge_val,
    const int* __restrict__ src, const int* __restrict__ dst,
    float* __restrict__ hacc) {
  int lane = threadIdx.x & 63;
  int wave = (blockIdx.x * blockDim.x + threadIdx.x) >> 6;
  int nwaves = (gridDim.x * blockDim.x) >> 6;
  for (int e = wave; e < N_EDGES; e += nwaves) {
    float v = edge_val[e];
    int s = src[e];
    int d = dst[e];
    float x = support1[(size_t)s * NHID + lane];
    atomicAdd(&hacc[(size_t)d * NHID + lane], v * x);
  }
}

// ---------------------------------------------------------------------------
// K3: h = relu(hacc + b1) * mask;  support2 = h @ W2   (thread = row)
// W2/b1 accesses are threadIdx-free -> scalar loads.
// ---------------------------------------------------------------------------
__global__ __launch_bounds__(256) void gemm2_kernel(
    const float* __restrict__ hacc, const float* __restrict__ b1,
    const float* __restrict__ mask, const float* __restrict__ W2,
    float* __restrict__ support2) {
  int row = blockIdx.x * blockDim.x + threadIdx.x;
  if (row >= N_NODES) return;
  const float* hr = hacc + (size_t)row * NHID;
  const float* mr = mask + (size_t)row * NHID;
  float h[NHID];
#pragma unroll
  for (int k = 0; k < NHID; k += 4) {
    float4 a = *(const float4*)(hr + k);
    float4 m = *(const float4*)(mr + k);
    float4 bb = *(const float4*)(b1 + k);
    h[k + 0] = fmaxf(a.x + bb.x, 0.f) * m.x;
    h[k + 1] = fmaxf(a.y + bb.y, 0.f) * m.y;
    h[k + 2] = fmaxf(a.z + bb.z, 0.f) * m.z;
    h[k + 3] = fmaxf(a.w + bb.w, 0.f) * m.w;
  }
  float acc[NOUT];
#pragma unroll
  for (int c = 0; c < NOUT; ++c) acc[c] = 0.f;
  for (int k = 0; k < NHID; ++k) {
    float hk = h[k];
    const float* w = W2 + (size_t)k * NOUT;
#pragma unroll
    for (int c = 0; c < NOUT; ++c) acc[c] = fmaf(hk, w[c], acc[c]);
  }
  float* o = support2 + (size_t)row * NOUT;
#pragma unroll
  for (int c = 0; c < NOUT; c += 4) {
    float4 v = {acc[c], acc[c + 1], acc[c + 2], acc[c + 3]};
    *(float4*)(o + c) = v;
  }
}

// ---------------------------------------------------------------------------
// K4a: out[i] = b2[i % 16]
// ---------------------------------------------------------------------------
__global__ __launch_bounds__(256) void init_out_kernel(
    const float* __restrict__ b2, float* __restrict__ out) {
  int i = blockIdx.x * blockDim.x + threadIdx.x;
  if (i < N_NODES * NOUT) out[i] = b2[i & 15];
}

// ---------------------------------------------------------------------------
// K4b: out[dst] += edge_val * support2[src]  (16-wide rows, 4 edges per wave)
// ---------------------------------------------------------------------------
__global__ __launch_bounds__(256) void spmm2_kernel(
    const float* __restrict__ support2, const float* __restrict__ edge_val,
    const int* __restrict__ src, const int* __restrict__ dst,
    float* __restrict__ out) {
  int t = blockIdx.x * blockDim.x + threadIdx.x;
  int c = t & 15;
  int e0 = t >> 4;
  int stride = (gridDim.x * blockDim.x) >> 4;
  for (int e = e0; e < N_EDGES; e += stride) {
    float v = edge_val[e];
    int s = src[e];
    int d = dst[e];
    float x = support2[(size_t)s * NOUT + c];
    atomicAdd(&out[(size_t)d * NOUT + c], v * x);
  }
}

extern "C" void kernel_launch(void* const* d_in, const int* in_sizes, int n_in,
                              void* d_out, int out_size, void* d_ws,
                              size_t ws_size, hipStream_t stream) {
  const float* emb = (const float*)d_in[0];
  const float* W1 = (const float*)d_in[1];
  const float* b1 = (const float*)d_in[2];
  const float* W2 = (const float*)d_in[3];
  const float* b2 = (const float*)d_in[4];
  const float* edge_val = (const float*)d_in[5];
  const float* mask = (const float*)d_in[6];
  const int* esrc = (const int*)d_in[7];
  const int* edst = (const int*)d_in[8];

  float* ws = (float*)d_ws;
  float* support1 = ws;                                // N_NODES*64 floats
  float* hacc = ws + (size_t)N_NODES * NHID;           // N_NODES*64 floats
  float* support2 = ws + 2 * (size_t)N_NODES * NHID;   // N_NODES*16 floats
  float* out = (float*)d_out;

  hipMemsetAsync(hacc, 0, (size_t)N_NODES * NHID * sizeof(float), stream);

  gemm1_kernel<<<(N_NODES + 255) / 256, 256, 0, stream>>>(emb, W1, support1);
  spmm1_kernel<<<2048, 256, 0, stream>>>(support1, edge_val, esrc, edst, hacc);
  gemm2_kernel<<<(N_NODES + 255) / 256, 256, 0, stream>>>(hacc, b1, mask, W2,
                                                          support2);
  init_out_kernel<<<(N_NODES * NOUT + 255) / 256, 256, 0, stream>>>(b2, out);
  spmm2_kernel<<<2048, 256, 0, stream>>>(support2, edge_val, esrc, edst, out);
}

// Round 3
// 411.376 us; speedup vs baseline: 1.3255x; 1.3255x over previous
//
#include <hip/hip_runtime.h>

#define N_NODES 100000
#define N_EDGES 1600000
#define NFEAT 256
#define NHID 64
#define NOUT 16
#define NB_SCAN 391  // ceil(N_NODES/256)

// ---------------------------------------------------------------------------
// CSR build step 1: histogram of dst
// ---------------------------------------------------------------------------
__global__ __launch_bounds__(256) void hist_kernel(const int* __restrict__ dst,
                                                   int* __restrict__ counts) {
  int t = blockIdx.x * blockDim.x + threadIdx.x;
  if (t < N_EDGES) atomicAdd(&counts[dst[t]], 1);
}

// ---------------------------------------------------------------------------
// CSR build step 2a: per-256-block inclusive scan of counts
// ---------------------------------------------------------------------------
__global__ __launch_bounds__(256) void scan1_kernel(
    const int* __restrict__ counts, int* __restrict__ scanTmp,
    int* __restrict__ blockSums) {
  __shared__ int s[256];
  int t = threadIdx.x;
  int i = blockIdx.x * 256 + t;
  int v = (i < N_NODES) ? counts[i] : 0;
  s[t] = v;
  __syncthreads();
  for (int off = 1; off < 256; off <<= 1) {
    int x = (t >= off) ? s[t - off] : 0;
    __syncthreads();
    s[t] += x;
    __syncthreads();
  }
  if (i < N_NODES) scanTmp[i] = s[t];
  if (t == 255) blockSums[blockIdx.x] = s[255];
}

// ---------------------------------------------------------------------------
// CSR build step 2b: single-block exclusive scan of block sums (NB_SCAN<=512)
// ---------------------------------------------------------------------------
__global__ __launch_bounds__(512) void scan2_kernel(
    const int* __restrict__ blockSums, int* __restrict__ blockOff) {
  __shared__ int s[512];
  int t = threadIdx.x;
  int v = (t < NB_SCAN) ? blockSums[t] : 0;
  s[t] = v;
  __syncthreads();
  for (int off = 1; off < 512; off <<= 1) {
    int x = (t >= off) ? s[t - off] : 0;
    __syncthreads();
    s[t] += x;
    __syncthreads();
  }
  if (t < NB_SCAN) blockOff[t] = s[t] - v;  // exclusive
}

// ---------------------------------------------------------------------------
// CSR build step 2c: row_start = exclusive scan; cursor = copy
// ---------------------------------------------------------------------------
__global__ __launch_bounds__(256) void scan3_kernel(
    const int* __restrict__ scanTmp, const int* __restrict__ counts,
    const int* __restrict__ blockOff, int* __restrict__ row_start,
    int* __restrict__ cursor) {
  int i = blockIdx.x * 256 + threadIdx.x;
  if (i < N_NODES) {
    int rs = scanTmp[i] - counts[i] + blockOff[blockIdx.x];
    row_start[i] = rs;
    cursor[i] = rs;
  }
}

// ---------------------------------------------------------------------------
// CSR build step 3: scatter edges into dst-sorted order, packing {src, val}
// ---------------------------------------------------------------------------
__global__ __launch_bounds__(256) void scatter_kernel(
    const int* __restrict__ src, const int* __restrict__ dst,
    const float* __restrict__ edge_val, int* __restrict__ cursor,
    int2* __restrict__ sorted_vs) {
  int t = blockIdx.x * blockDim.x + threadIdx.x;
  if (t >= N_EDGES) return;
  int d = dst[t];
  int p = atomicAdd(&cursor[d], 1);
  int2 vs;
  vs.x = src[t];
  vs.y = __float_as_int(edge_val[t]);
  sorted_vs[p] = vs;
}

// ---------------------------------------------------------------------------
// K1: support1 = emb @ W1   [100000,256] @ [256,64]
// thread = one row; W1 accesses are threadIdx-free -> scalar loads.
// ---------------------------------------------------------------------------
__global__ __launch_bounds__(256) void gemm1_kernel(
    const float* __restrict__ emb, const float* __restrict__ W1,
    float* __restrict__ out) {
  int row = blockIdx.x * blockDim.x + threadIdx.x;
  if (row >= N_NODES) return;
  float acc[NHID];
#pragma unroll
  for (int c = 0; c < NHID; ++c) acc[c] = 0.f;
  const float* er = emb + (size_t)row * NFEAT;
  for (int k = 0; k < NFEAT; k += 4) {
    float4 e = *(const float4*)(er + k);
#pragma unroll
    for (int j = 0; j < 4; ++j) {
      const float* w = W1 + (size_t)(k + j) * NHID;
      float ej = j == 0 ? e.x : (j == 1 ? e.y : (j == 2 ? e.z : e.w));
#pragma unroll
      for (int c = 0; c < NHID; ++c) acc[c] = fmaf(ej, w[c], acc[c]);
    }
  }
  float* o = out + (size_t)row * NHID;
#pragma unroll
  for (int c = 0; c < NHID; c += 4) {
    float4 v = {acc[c], acc[c + 1], acc[c + 2], acc[c + 3]};
    *(float4*)(o + c) = v;
  }
}

// ---------------------------------------------------------------------------
// K2 (fused): wave per dst row.
//   acc[lane] = sum_e val_e * support1[src_e][lane]        (CSR, no atomics)
//   h = relu(acc + b1) * mask
//   support2[row][c] = sum_k h[k] * W2[k][c]               (LDS + shfl reduce)
// ---------------------------------------------------------------------------
__global__ __launch_bounds__(256) void spmm1_fused_kernel(
    const float* __restrict__ support1, const int2* __restrict__ sorted_vs,
    const int* __restrict__ row_start, const int* __restrict__ counts,
    const float* __restrict__ b1, const float* __restrict__ mask,
    const float* __restrict__ W2, float* __restrict__ support2) {
  int wave = (blockIdx.x * blockDim.x + threadIdx.x) >> 6;
  int lane = threadIdx.x & 63;
  int wib = threadIdx.x >> 6;
  if (wave >= N_NODES) return;  // exact grid: never taken
  int r = wave;
  int beg = row_start[r];
  int end = beg + counts[r];
  float acc = 0.f;
#pragma unroll 4
  for (int e = beg; e < end; ++e) {
    int2 vs = sorted_vs[e];
    acc = fmaf(__int_as_float(vs.y), support1[(size_t)vs.x * NHID + lane],
               acc);
  }
  float h = fmaxf(acc + b1[lane], 0.f) * mask[(size_t)r * NHID + lane];

  __shared__ float hsh[4][NHID];
  hsh[wib][lane] = h;
  __syncthreads();
  int q = lane >> 4;   // 0..3 : k-quarter
  int c = lane & 15;   // output col
  float p = 0.f;
#pragma unroll
  for (int i = 0; i < 16; ++i) {
    int k = q * 16 + i;
    p = fmaf(hsh[wib][k], W2[k * NOUT + c], p);
  }
  p += __shfl_xor(p, 16);
  p += __shfl_xor(p, 32);
  if (lane < 16) support2[(size_t)r * NOUT + lane] = p;
}

// ---------------------------------------------------------------------------
// K3: out[row][c] = sum_e val_e * support2[src_e][c] + b2[c]
// 16 lanes per row, 4 rows per wave. CSR, no atomics, no init pass.
// ---------------------------------------------------------------------------
__global__ __launch_bounds__(256) void spmm2_csr_kernel(
    const float* __restrict__ support2, const int2* __restrict__ sorted_vs,
    const int* __restrict__ row_start, const int* __restrict__ counts,
    const float* __restrict__ b2, float* __restrict__ out) {
  int t = blockIdx.x * blockDim.x + threadIdx.x;
  int r = t >> 4;
  int c = t & 15;
  if (r >= N_NODES) return;
  int beg = row_start[r];
  int end = beg + counts[r];
  float acc = 0.f;
#pragma unroll 4
  for (int e = beg; e < end; ++e) {
    int2 vs = sorted_vs[e];
    acc = fmaf(__int_as_float(vs.y), support2[(size_t)vs.x * NOUT + c], acc);
  }
  out[(size_t)r * NOUT + c] = acc + b2[c];
}

extern "C" void kernel_launch(void* const* d_in, const int* in_sizes, int n_in,
                              void* d_out, int out_size, void* d_ws,
                              size_t ws_size, hipStream_t stream) {
  const float* emb = (const float*)d_in[0];
  const float* W1 = (const float*)d_in[1];
  const float* b1 = (const float*)d_in[2];
  const float* W2 = (const float*)d_in[3];
  const float* b2 = (const float*)d_in[4];
  const float* edge_val = (const float*)d_in[5];
  const float* mask = (const float*)d_in[6];
  const int* esrc = (const int*)d_in[7];
  const int* edst = (const int*)d_in[8];

  // workspace layout (element offsets in 4-byte units; int2 slots 8B-aligned)
  float* ws = (float*)d_ws;
  float* support1 = ws;                               // 6,400,000 f
  int2* sorted_vs = (int2*)(ws + 6400000);            // 1,600,000 int2 (even)
  float* support2 = ws + 6400000 + 3200000;           // 1,600,000 f
  int* counts = (int*)(ws + 11200000);                // 100,000 i
  int* scanTmp = counts + 100000;                     // 100,000 i
  int* row_start = scanTmp + 100000;                  // 100,000 i
  int* cursor = row_start + 100000;                   // 100,000 i
  int* blockSums = cursor + 100000;                   // 512 i
  int* blockOff = blockSums + 512;                    // 512 i
  float* out = (float*)d_out;

  hipMemsetAsync(counts, 0, N_NODES * sizeof(int), stream);

  // CSR build (reused by both spmm passes)
  hist_kernel<<<(N_EDGES + 255) / 256, 256, 0, stream>>>(edst, counts);
  scan1_kernel<<<NB_SCAN, 256, 0, stream>>>(counts, scanTmp, blockSums);
  scan2_kernel<<<1, 512, 0, stream>>>(blockSums, blockOff);
  scan3_kernel<<<NB_SCAN, 256, 0, stream>>>(scanTmp, counts, blockOff,
                                            row_start, cursor);
  scatter_kernel<<<(N_EDGES + 255) / 256, 256, 0, stream>>>(
      esrc, edst, edge_val, cursor, sorted_vs);

  // dense + sparse pipeline
  gemm1_kernel<<<(N_NODES + 255) / 256, 256, 0, stream>>>(emb, W1, support1);
  spmm1_fused_kernel<<<N_NODES / 4, 256, 0, stream>>>(
      support1, sorted_vs, row_start, counts, b1, mask, W2, support2);
  spmm2_csr_kernel<<<(N_NODES * NOUT + 255) / 256, 256, 0, stream>>>(
      support2, sorted_vs, row_start, counts, b2, out);
}

// Round 4
// 380.267 us; speedup vs baseline: 1.4339x; 1.0818x over previous
//
#include <hip/hip_runtime.h>

#define N_NODES 100000
#define N_EDGES 1600000
#define NFEAT 256
#define NHID 64
#define NOUT 16
#define NB_SCAN 391  // ceil(N_NODES/256)

// ---------------------------------------------------------------------------
// CSR build step 1: histogram of dst
// ---------------------------------------------------------------------------
__global__ __launch_bounds__(256) void hist_kernel(const int* __restrict__ dst,
                                                   int* __restrict__ counts) {
  int t = blockIdx.x * blockDim.x + threadIdx.x;
  if (t < N_EDGES) atomicAdd(&counts[dst[t]], 1);
}

// ---------------------------------------------------------------------------
// CSR build step 2a: per-256-block inclusive scan of counts
// ---------------------------------------------------------------------------
__global__ __launch_bounds__(256) void scan1_kernel(
    const int* __restrict__ counts, int* __restrict__ scanTmp,
    int* __restrict__ blockSums) {
  __shared__ int s[256];
  int t = threadIdx.x;
  int i = blockIdx.x * 256 + t;
  int v = (i < N_NODES) ? counts[i] : 0;
  s[t] = v;
  __syncthreads();
  for (int off = 1; off < 256; off <<= 1) {
    int x = (t >= off) ? s[t - off] : 0;
    __syncthreads();
    s[t] += x;
    __syncthreads();
  }
  if (i < N_NODES) scanTmp[i] = s[t];
  if (t == 255) blockSums[blockIdx.x] = s[255];
}

// ---------------------------------------------------------------------------
// CSR build step 2b: single-block exclusive scan of block sums (NB_SCAN<=512)
// ---------------------------------------------------------------------------
__global__ __launch_bounds__(512) void scan2_kernel(
    const int* __restrict__ blockSums, int* __restrict__ blockOff) {
  __shared__ int s[512];
  int t = threadIdx.x;
  int v = (t < NB_SCAN) ? blockSums[t] : 0;
  s[t] = v;
  __syncthreads();
  for (int off = 1; off < 512; off <<= 1) {
    int x = (t >= off) ? s[t - off] : 0;
    __syncthreads();
    s[t] += x;
    __syncthreads();
  }
  if (t < NB_SCAN) blockOff[t] = s[t] - v;  // exclusive
}

// ---------------------------------------------------------------------------
// CSR build step 2c: row_start = exclusive scan; cursor = copy
// ---------------------------------------------------------------------------
__global__ __launch_bounds__(256) void scan3_kernel(
    const int* __restrict__ scanTmp, const int* __restrict__ counts,
    const int* __restrict__ blockOff, int* __restrict__ row_start,
    int* __restrict__ cursor) {
  int i = blockIdx.x * 256 + threadIdx.x;
  if (i < N_NODES) {
    int rs = scanTmp[i] - counts[i] + blockOff[blockIdx.x];
    row_start[i] = rs;
    cursor[i] = rs;
  }
}

// ---------------------------------------------------------------------------
// CSR build step 3: scatter edges into dst-sorted order, packing {src, val}
// ---------------------------------------------------------------------------
__global__ __launch_bounds__(256) void scatter_kernel(
    const int* __restrict__ src, const int* __restrict__ dst,
    const float* __restrict__ edge_val, int* __restrict__ cursor,
    int2* __restrict__ sorted_vs) {
  int t = blockIdx.x * blockDim.x + threadIdx.x;
  if (t >= N_EDGES) return;
  int d = dst[t];
  int p = atomicAdd(&cursor[d], 1);
  int2 vs;
  vs.x = src[t];
  vs.y = __float_as_int(edge_val[t]);
  sorted_vs[p] = vs;
}

// ---------------------------------------------------------------------------
// K1: support1 = emb @ W1   [100000,256] @ [256,64]
// Block = 64 rows x 4 waves; wave wq owns col-quarter [wq*16, wq*16+16).
// lane = row. acc[16]/thread. W1 base hoisted to SGPR via readfirstlane ->
// s_load_dwordx16 per k (scalar pipe), emb streamed 16 floats/chunk (4
// independent dwordx4 in flight). Waves of a block share emb rows via L1.
// ---------------------------------------------------------------------------
__global__ __launch_bounds__(256) void gemm1_kernel(
    const float* __restrict__ emb, const float* __restrict__ W1,
    float* __restrict__ out) {
  int lane = threadIdx.x & 63;
  // wave id in block, forced into an SGPR so W1 addressing stays scalar
  int wq = __builtin_amdgcn_readfirstlane(threadIdx.x >> 6);
  int row = blockIdx.x * 64 + lane;
  int rclamp = row < N_NODES ? row : (N_NODES - 1);
  const float* er = emb + (size_t)rclamp * NFEAT;
  const float* w1q = W1 + wq * 16;  // scalar base

  float acc[16];
#pragma unroll
  for (int c = 0; c < 16; ++c) acc[c] = 0.f;

  for (int k0 = 0; k0 < NFEAT; k0 += 16) {
    float eb[16];
#pragma unroll
    for (int q = 0; q < 4; ++q)
      *(float4*)(eb + 4 * q) = *(const float4*)(er + k0 + 4 * q);
#pragma unroll
    for (int j = 0; j < 16; ++j) {
      const float* w = w1q + (size_t)(k0 + j) * NHID;  // lane-invariant
#pragma unroll
      for (int c = 0; c < 16; ++c) acc[c] = fmaf(eb[j], w[c], acc[c]);
    }
  }

  if (row < N_NODES) {
    float* o = out + (size_t)row * NHID + wq * 16;
#pragma unroll
    for (int c = 0; c < 16; c += 4) {
      float4 v = {acc[c], acc[c + 1], acc[c + 2], acc[c + 3]};
      *(float4*)(o + c) = v;
    }
  }
}

// ---------------------------------------------------------------------------
// K2 (fused): wave per dst row.
//   acc[lane] = sum_e val_e * support1[src_e][lane]        (CSR, no atomics)
//   h = relu(acc + b1) * mask
//   support2[row][c] = sum_k h[k] * W2[k][c]               (LDS + shfl reduce)
// ---------------------------------------------------------------------------
__global__ __launch_bounds__(256) void spmm1_fused_kernel(
    const float* __restrict__ support1, const int2* __restrict__ sorted_vs,
    const int* __restrict__ row_start, const int* __restrict__ counts,
    const float* __restrict__ b1, const float* __restrict__ mask,
    const float* __restrict__ W2, float* __restrict__ support2) {
  int wave = (blockIdx.x * blockDim.x + threadIdx.x) >> 6;
  int lane = threadIdx.x & 63;
  int wib = threadIdx.x >> 6;
  if (wave >= N_NODES) return;  // exact grid: never taken
  int r = wave;
  int beg = row_start[r];
  int end = beg + counts[r];
  float acc = 0.f;
#pragma unroll 4
  for (int e = beg; e < end; ++e) {
    int2 vs = sorted_vs[e];
    acc = fmaf(__int_as_float(vs.y), support1[(size_t)vs.x * NHID + lane],
               acc);
  }
  float h = fmaxf(acc + b1[lane], 0.f) * mask[(size_t)r * NHID + lane];

  __shared__ float hsh[4][NHID];
  hsh[wib][lane] = h;
  __syncthreads();
  int q = lane >> 4;   // 0..3 : k-quarter
  int c = lane & 15;   // output col
  float p = 0.f;
#pragma unroll
  for (int i = 0; i < 16; ++i) {
    int k = q * 16 + i;
    p = fmaf(hsh[wib][k], W2[k * NOUT + c], p);
  }
  p += __shfl_xor(p, 16);
  p += __shfl_xor(p, 32);
  if (lane < 16) support2[(size_t)r * NOUT + lane] = p;
}

// ---------------------------------------------------------------------------
// K3: out[row][c] = sum_e val_e * support2[src_e][c] + b2[c]
// 16 lanes per row, 4 rows per wave. CSR, no atomics, no init pass.
// ---------------------------------------------------------------------------
__global__ __launch_bounds__(256) void spmm2_csr_kernel(
    const float* __restrict__ support2, const int2* __restrict__ sorted_vs,
    const int* __restrict__ row_start, const int* __restrict__ counts,
    const float* __restrict__ b2, float* __restrict__ out) {
  int t = blockIdx.x * blockDim.x + threadIdx.x;
  int r = t >> 4;
  int c = t & 15;
  if (r >= N_NODES) return;
  int beg = row_start[r];
  int end = beg + counts[r];
  float acc = 0.f;
#pragma unroll 4
  for (int e = beg; e < end; ++e) {
    int2 vs = sorted_vs[e];
    acc = fmaf(__int_as_float(vs.y), support2[(size_t)vs.x * NOUT + c], acc);
  }
  out[(size_t)r * NOUT + c] = acc + b2[c];
}

extern "C" void kernel_launch(void* const* d_in, const int* in_sizes, int n_in,
                              void* d_out, int out_size, void* d_ws,
                              size_t ws_size, hipStream_t stream) {
  const float* emb = (const float*)d_in[0];
  const float* W1 = (const float*)d_in[1];
  const float* b1 = (const float*)d_in[2];
  const float* W2 = (const float*)d_in[3];
  const float* b2 = (const float*)d_in[4];
  const float* edge_val = (const float*)d_in[5];
  const float* mask = (const float*)d_in[6];
  const int* esrc = (const int*)d_in[7];
  const int* edst = (const int*)d_in[8];

  // workspace layout (element offsets in 4-byte units; int2 slots 8B-aligned)
  float* ws = (float*)d_ws;
  float* support1 = ws;                               // 6,400,000 f
  int2* sorted_vs = (int2*)(ws + 6400000);            // 1,600,000 int2 (even)
  float* support2 = ws + 6400000 + 3200000;           // 1,600,000 f
  int* counts = (int*)(ws + 11200000);                // 100,000 i
  int* scanTmp = counts + 100000;                     // 100,000 i
  int* row_start = scanTmp + 100000;                  // 100,000 i
  int* cursor = row_start + 100000;                   // 100,000 i
  int* blockSums = cursor + 100000;                   // 512 i
  int* blockOff = blockSums + 512;                    // 512 i
  float* out = (float*)d_out;

  hipMemsetAsync(counts, 0, N_NODES * sizeof(int), stream);

  // CSR build (reused by both spmm passes)
  hist_kernel<<<(N_EDGES + 255) / 256, 256, 0, stream>>>(edst, counts);
  scan1_kernel<<<NB_SCAN, 256, 0, stream>>>(counts, scanTmp, blockSums);
  scan2_kernel<<<1, 512, 0, stream>>>(blockSums, blockOff);
  scan3_kernel<<<NB_SCAN, 256, 0, stream>>>(scanTmp, counts, blockOff,
                                            row_start, cursor);
  scatter_kernel<<<(N_EDGES + 255) / 256, 256, 0, stream>>>(
      esrc, edst, edge_val, cursor, sorted_vs);

  // dense + sparse pipeline
  gemm1_kernel<<<(N_NODES + 63) / 64, 256, 0, stream>>>(emb, W1, support1);
  spmm1_fused_kernel<<<N_NODES / 4, 256, 0, stream>>>(
      support1, sorted_vs, row_start, counts, b1, mask, W2, support2);
  spmm2_csr_kernel<<<(N_NODES * NOUT + 255) / 256, 256, 0, stream>>>(
      support2, sorted_vs, row_start, counts, b2, out);
}